// Round 5
// baseline (253.616 us; speedup 1.0000x reference)
//
#include <hip/hip_runtime.h>
#include <cmath>

#define N_ 32
#define B_ 64
#define T_ 8192
#define NBLK1 1024             // 16 c-groups (512 t) * 64 b ; bid = cg*64 + b
#define PS 2176                // 2048 gram (pp|pn) + 128 stats

typedef _Float16 half8 __attribute__((ext_vector_type(8)));
typedef float floatx4 __attribute__((ext_vector_type(4)));

// convert 8 f32 -> f16 fragment, accumulating sum and sum-of-squares on the way
__device__ __forceinline__ half8 cvt8(const float4 v0, const float4 v1,
                                      float& s, float& s2) {
    s += v0.x + v0.y + v0.z + v0.w + v1.x + v1.y + v1.z + v1.w;
    s2 = fmaf(v0.x, v0.x, s2); s2 = fmaf(v0.y, v0.y, s2);
    s2 = fmaf(v0.z, v0.z, s2); s2 = fmaf(v0.w, v0.w, s2);
    s2 = fmaf(v1.x, v1.x, s2); s2 = fmaf(v1.y, v1.y, s2);
    s2 = fmaf(v1.z, v1.z, s2); s2 = fmaf(v1.w, v1.w, s2);
    half8 r = {(_Float16)v0.x, (_Float16)v0.y, (_Float16)v0.z, (_Float16)v0.w,
               (_Float16)v1.x, (_Float16)v1.y, (_Float16)v1.z, (_Float16)v1.w};
    return r;
}

// ---------------- Stage 1: TLP-saturated global->register MFMA ----------------
// Round-4 post-mortem: sched_barrier couldn't pin 32 loads (VGPR stayed 64 ->
// ~4 serialized convoys, 53us latency-bound at only 16 waves/CU launched).
// Fix: get latency hiding from THREAD parallelism, not per-wave ILP.
// grid 1024 (cg,b), block 512 = 8 waves, each wave owns a 64-t slice:
// 4 blocks/CU x 8 waves = 32 waves/CU (100% capacity) at VGPR<=64
// (__launch_bounds__(512,8)). Each wave: 16 dwordx4 in ~2 convoys; 32 waves/CU
// keep ~256KB/CU outstanding. Epilogue: single 8.7KB LDS buffer + ds_add_f32
// atomics (2 barriers), so LDS never limits blocks/CU.
__global__ __launch_bounds__(512, 8)
void k_stage1(const float* __restrict__ pos, const float* __restrict__ neg,
              float* __restrict__ partial, double* __restrict__ accs,
              unsigned* __restrict__ ctr) {
    __shared__ __align__(16) float red_s[PS];   // 8704 B
    const int bid = blockIdx.x;
    const int b = bid & 63, cg = bid >> 6;      // bid = cg*64 + b
    const int tid = threadIdx.x;
    const int w = tid >> 6, lane = tid & 63;    // w = 0..7
    const int m = lane & 15, h = lane >> 4;     // A-frag coords

    if (bid == 0 && tid == 0) { accs[0] = 0.0; accs[1] = 0.0; *ctr = 0u; }

    const long tb = (long)cg * 512 + w * 64 + h * 8;
    const float4* pa0 = (const float4*)(pos + ((long)m * B_ + b) * T_ + tb);
    const float4* pa1 = (const float4*)(pos + ((long)(m + 16) * B_ + b) * T_ + tb);
    const float4* pb0 = (const float4*)(neg + ((long)m * B_ + b) * T_ + tb);
    const float4* pb1 = (const float4*)(neg + ((long)(m + 16) * B_ + b) * T_ + tb);

    // 16 dwordx4 per wave (2 k-steps of K=32)
    float4 a0[2][2], a1[2][2], b0[2][2], b1[2][2];
#pragma unroll
    for (int kk = 0; kk < 2; ++kk) {
        a0[kk][0] = pa0[kk * 8]; a0[kk][1] = pa0[kk * 8 + 1];
        a1[kk][0] = pa1[kk * 8]; a1[kk][1] = pa1[kk * 8 + 1];
        b0[kk][0] = pb0[kk * 8]; b0[kk][1] = pb0[kk * 8 + 1];
        b1[kk][0] = pb1[kk * 8]; b1[kk][1] = pb1[kk * 8 + 1];
    }

    // zero the shared accumulator while loads are in flight
    for (int i = tid; i < PS; i += 512) red_s[i] = 0.f;

    floatx4 cPP00 = {}, cPP01 = {}, cPP11 = {};
    floatx4 cPN00 = {}, cPN01 = {}, cPN10 = {}, cPN11 = {};
    float sxl = 0.f, sxl2 = 0.f, sxh = 0.f, sxh2 = 0.f;
    float syl = 0.f, syl2 = 0.f, syh = 0.f, syh2 = 0.f;

#pragma unroll
    for (int kk = 0; kk < 2; ++kk) {
        half8 fa0 = cvt8(a0[kk][0], a0[kk][1], sxl, sxl2);
        half8 fa1 = cvt8(a1[kk][0], a1[kk][1], sxh, sxh2);
        half8 fb0 = cvt8(b0[kk][0], b0[kk][1], syl, syl2);
        half8 fb1 = cvt8(b1[kk][0], b1[kk][1], syh, syh2);
        // mfma(rowfragX, rowfragY) = X . Y^T
        cPP00 = __builtin_amdgcn_mfma_f32_16x16x32_f16(fa0, fa0, cPP00, 0, 0, 0);
        cPP01 = __builtin_amdgcn_mfma_f32_16x16x32_f16(fa0, fa1, cPP01, 0, 0, 0);
        cPP11 = __builtin_amdgcn_mfma_f32_16x16x32_f16(fa1, fa1, cPP11, 0, 0, 0);
        cPN00 = __builtin_amdgcn_mfma_f32_16x16x32_f16(fa0, fb0, cPN00, 0, 0, 0);
        cPN01 = __builtin_amdgcn_mfma_f32_16x16x32_f16(fa0, fb1, cPN01, 0, 0, 0);
        cPN10 = __builtin_amdgcn_mfma_f32_16x16x32_f16(fa1, fb0, cPN10, 0, 0, 0);
        cPN11 = __builtin_amdgcn_mfma_f32_16x16x32_f16(fa1, fb1, cPN11, 0, 0, 0);
    }

    // fold the 4 h-lane slices of each row's stats (lanes m, m+16, m+32, m+48)
    sxl += __shfl_xor(sxl, 16);   sxl += __shfl_xor(sxl, 32);
    sxl2 += __shfl_xor(sxl2, 16); sxl2 += __shfl_xor(sxl2, 32);
    sxh += __shfl_xor(sxh, 16);   sxh += __shfl_xor(sxh, 32);
    sxh2 += __shfl_xor(sxh2, 16); sxh2 += __shfl_xor(sxh2, 32);
    syl += __shfl_xor(syl, 16);   syl += __shfl_xor(syl, 32);
    syl2 += __shfl_xor(syl2, 16); syl2 += __shfl_xor(syl2, 32);
    syh += __shfl_xor(syh, 16);   syh += __shfl_xor(syh, 32);
    syh2 += __shfl_xor(syh2, 16); syh2 += __shfl_xor(syh2, 32);

    __syncthreads();   // zero-init visible to all

    // cross-wave combine via LDS float atomics (ds_add_f32, no return needed).
    // C/D layout (m89-verified): col = lane&15, row = (lane>>4)*4 + reg
#pragma unroll
    for (int reg = 0; reg < 4; ++reg) {
        const int r = h * 4 + reg;
        atomicAdd(&red_s[r * 32 + m],                    cPP00[reg]);
        atomicAdd(&red_s[r * 32 + 16 + m],               cPP01[reg]);
        atomicAdd(&red_s[(16 + r) * 32 + 16 + m],        cPP11[reg]);
        atomicAdd(&red_s[1024 + r * 32 + m],             cPN00[reg]);
        atomicAdd(&red_s[1024 + r * 32 + 16 + m],        cPN01[reg]);
        atomicAdd(&red_s[1024 + (16 + r) * 32 + m],      cPN10[reg]);
        atomicAdd(&red_s[1024 + (16 + r) * 32 + 16 + m], cPN11[reg]);
    }
    {
        const int row = (h & 1) * 16 + m;
        const int base = 2048 + (h >> 1) * 64;   // h<2: sx block, h>=2: sy block
        const float s1 = (h == 0) ? sxl : (h == 1) ? sxh : (h == 2) ? syl : syh;
        const float s2 = (h == 0) ? sxl2 : (h == 1) ? sxh2 : (h == 2) ? syl2 : syh2;
        atomicAdd(&red_s[base + row], s1);
        atomicAdd(&red_s[base + 32 + row], s2);
    }
    __syncthreads();

    // coalesced contiguous store: partial[bid][o]
    for (int i = tid; i < PS; i += 512)
        partial[(long)bid * PS + i] = red_s[i];
}

// ---------------- Stage 2: reduce 16 chunk partials -> per-b stats (coalesced) ----
// grid (17, 64), block 128: one thread per output element; reads are coalesced
// (consecutive threads -> consecutive o), writes red[b][o] contiguous.
__global__ void k_reduce(const float* __restrict__ partial, float* __restrict__ red) {
    const int b = blockIdx.y;
    const int o = blockIdx.x * 128 + threadIdx.x;   // 0..2175
    float s = 0.f;
#pragma unroll
    for (int c = 0; c < 16; ++c) s += partial[(long)(c * 64 + b) * PS + o];
    red[(long)b * PS + o] = s;
}

// ---------------- Stage 3 (fused): pearson + exp + block sums + final ----------
// one wave per (mat,n,m) entry; lane = b. 5 strided loads per wave from the
// 557KB L2-resident red. Block partials -> 2 double atomicAdds; last block
// (counter) computes the final scalar. 3 launches total.
__global__ __launch_bounds__(256)
void k_entries(const float* __restrict__ red, double* __restrict__ accs,
               unsigned* __restrict__ ctr, float* __restrict__ out) {
    const int tid = threadIdx.x;
    const int w = tid >> 6, lane = tid & 63;
    const int entry = blockIdx.x * 4 + w;
    const int mat = entry >> 10;        // 0 = pp, 1 = pn
    const int idx = entry & 1023;
    const int n = idx >> 5, m = idx & 31;

    const float* rb = red + (long)lane * PS;
    const float g    = rb[mat * 1024 + idx];
    const float sxn  = rb[2048 + n];
    const float sx2n = rb[2080 + n];
    const float sym  = rb[mat ? 2112 + m : 2048 + m];
    const float sy2m = rb[mat ? 2144 + m : 2080 + m];

    double num = (double)T_ * (double)g - (double)sxn * (double)sym;
    double vx = (double)T_ * (double)sx2n - (double)sxn * (double)sxn;
    double vy = (double)T_ * (double)sy2m - (double)sym * (double)sym;
    double contrib = 1.0 - num / sqrt(vx * vy);

#pragma unroll
    for (int off = 32; off; off >>= 1) contrib += __shfl_down(contrib, off);

    __shared__ double s_pos[4], s_neg[4];
    if (lane == 0) {
        double d = contrib * (1.0 / B_);
        double term = exp(d / 0.08);
        double p = 0.0, q = 0.0;
        if (mat == 0) { if (n < m) p = term; }   // strict upper triangle
        else q = term;
        s_pos[w] = p; s_neg[w] = q;
    }
    __syncthreads();
    if (tid == 0) {
        atomicAdd(&accs[0], s_pos[0] + s_pos[1] + s_pos[2] + s_pos[3]);
        atomicAdd(&accs[1], s_neg[0] + s_neg[1] + s_neg[2] + s_neg[3]);
        __threadfence();
        const unsigned old = atomicAdd(ctr, 1u);
        if (old == gridDim.x - 1) {              // last block finalizes
            __threadfence();
            const double p = ((volatile double*)accs)[0];
            const double q = ((volatile double*)accs)[1];
            out[0] = (float)log10(p / q + 1.0);
        }
    }
}

extern "C" void kernel_launch(void* const* d_in, const int* in_sizes, int n_in,
                              void* d_out, int out_size, void* d_ws, size_t ws_size,
                              hipStream_t stream) {
    (void)in_sizes; (void)n_in; (void)out_size; (void)ws_size;
    const float* pos = (const float*)d_in[0];
    const float* neg = (const float*)d_in[1];
    float* out = (float*)d_out;

    char* ws = (char*)d_ws;
    float* partial = (float*)ws;                               // 1024*2176*4 = 8,912,896 B
    float* red = (float*)(ws + (size_t)NBLK1 * PS * 4);        //   64*2176*4 =   557,056 B
    double* accs = (double*)(ws + (size_t)NBLK1 * PS * 4 + (size_t)64 * PS * 4);
    unsigned* ctr = (unsigned*)((char*)accs + 16);

    k_stage1<<<NBLK1, 512, 0, stream>>>(pos, neg, partial, accs, ctr);
    k_reduce<<<dim3(17, 64), 128, 0, stream>>>(partial, red);
    k_entries<<<512, 256, 0, stream>>>(red, accs, ctr, out);
}

// Round 6
// 173.508 us; speedup vs baseline: 1.4617x; 1.4617x over previous
//
#include <hip/hip_runtime.h>
#include <cmath>

#define N_ 32
#define B_ 64
#define T_ 8192
#define NBLK1 1024             // 16 c-groups (512 t) * 64 b ; bid = cg*64 + b
#define PS 2176                // 2048 gram (pp|pn) + 128 stats

typedef _Float16 half4 __attribute__((ext_vector_type(4)));
typedef _Float16 half8 __attribute__((ext_vector_type(8)));
typedef float floatx4 __attribute__((ext_vector_type(4)));

// ---------------- Stage 1: streaming loads -> swizzled LDS f16 tile -> MFMA ----
// Rounds 0/3/4 all plateaued at 47-53us (2.5-2.8 TB/s logical) with loads that
// scatter each instruction across 16 rows 32KB apart. This version makes every
// global load instruction a CONTIGUOUS 1KB wave-block (wave w streams rows
// 4w..4w+3), staging f32->f16 into a 64KB XOR-swizzled LDS tile; the MFMA
// fragment layout is recovered from LDS. One barrier per block. Swizzle
// byte^=(row&7)<<4 makes ds_write AND the 16-row ds_read_b128 fragment reads
// beat-conflict-free. LDS=65536 -> 2 blocks/CU = 16 waves/CU; VGPR cap 128
// (round-5 lesson: never cap below the live set -> scratch spill disaster).
__global__ __launch_bounds__(512, 4)
void k_stage1(const float* __restrict__ pos, const float* __restrict__ neg,
              float* __restrict__ partial, double* __restrict__ accs,
              unsigned* __restrict__ ctr) {
    __shared__ __align__(16) _Float16 tile[2][32][512];   // 65536 B, swizzled
    const int bid = blockIdx.x;
    const int b = bid & 63, cg = bid >> 6;      // bid = cg*64 + b
    const int tid = threadIdx.x;
    const int w = tid >> 6, lane = tid & 63;    // 8 waves
    const int m = lane & 15, h = lane >> 4;     // A-frag coords (MFMA phase)

    if (bid == 0 && tid == 0) { accs[0] = 0.0; accs[1] = 0.0; *ctr = 0u; }

    float* out = partial + (long)bid * PS;
    const long cbase = (long)cg * 512;

    // ---- staging: wave w owns rows 4w..4w+3 of BOTH tensors.
    // Each load: lane reads float4 at (row, cbase + j*256 + lane*4) -> the wave
    // covers 1KB contiguous. 16 loads issued up front (streaming).
    float4 v[16];   // [tau*8 + s*2 + j]
#pragma unroll
    for (int s = 0; s < 4; ++s) {
        const float4* prow = (const float4*)(pos + ((long)(4 * w + s) * B_ + b) * T_ + cbase);
        v[s * 2 + 0] = prow[lane];
        v[s * 2 + 1] = prow[64 + lane];
    }
#pragma unroll
    for (int s = 0; s < 4; ++s) {
        const float4* nrow = (const float4*)(neg + ((long)(4 * w + s) * B_ + b) * T_ + cbase);
        v[8 + s * 2 + 0] = nrow[lane];
        v[8 + s * 2 + 1] = nrow[64 + lane];
    }

    // stats accumulate per (tensor, row): all 64 lanes hold the same row set
    float st[16];
#pragma unroll
    for (int i = 0; i < 16; ++i) st[i] = 0.f;

#pragma unroll
    for (int t2 = 0; t2 < 2; ++t2) {
#pragma unroll
        for (int s = 0; s < 4; ++s) {
            const int r = 4 * w + s;
            const int xr = (r & 7) << 4;           // swizzle for this row
#pragma unroll
            for (int j = 0; j < 2; ++j) {
                float4 q = v[t2 * 8 + s * 2 + j];
                st[t2 * 8 + s * 2 + 0] += q.x + q.y + q.z + q.w;
                float sq = st[t2 * 8 + s * 2 + 1];
                sq = fmaf(q.x, q.x, sq); sq = fmaf(q.y, q.y, sq);
                sq = fmaf(q.z, q.z, sq); sq = fmaf(q.w, q.w, sq);
                st[t2 * 8 + s * 2 + 1] = sq;
                half4 hq = {(_Float16)q.x, (_Float16)q.y, (_Float16)q.z, (_Float16)q.w};
                char* dst = (char*)&tile[t2][r][0] + ((j * 512 + lane * 8) ^ xr);
                *(half4*)dst = hq;
            }
        }
    }

    // full-wave butterfly for the 16 per-row stats; lane 0 stores to global
#pragma unroll
    for (int i = 0; i < 16; ++i) {
        float x = st[i];
        x += __shfl_xor(x, 1);  x += __shfl_xor(x, 2);  x += __shfl_xor(x, 4);
        x += __shfl_xor(x, 8);  x += __shfl_xor(x, 16); x += __shfl_xor(x, 32);
        st[i] = x;
    }
    if (lane == 0) {
#pragma unroll
        for (int t2 = 0; t2 < 2; ++t2)
#pragma unroll
            for (int s = 0; s < 4; ++s) {
                out[2048 + t2 * 64 + (4 * w + s)]      = st[t2 * 8 + s * 2 + 0];
                out[2048 + t2 * 64 + 32 + (4 * w + s)] = st[t2 * 8 + s * 2 + 1];
            }
    }

    __syncthreads();   // the only barrier

    // ---- MFMA phase: wave -> (mat, qi, qj) quadrant (round-0 verified mapping)
    const int mat = w >> 2, qi = (w >> 1) & 1, qj = w & 1;
    const int arow = qi * 16 + m, brow = qj * 16 + m;
    const char* tA = (const char*)&tile[0][arow][0];
    const char* tB = (const char*)&tile[mat][brow][0];
    const int xa = (arow & 7) << 4, xb = (brow & 7) << 4;

    floatx4 acc = {};
#pragma unroll
    for (int kk = 0; kk < 16; ++kk) {
        half8 af = *(const half8*)(tA + ((kk * 64 + h * 16) ^ xa));
        half8 bf = *(const half8*)(tB + ((kk * 64 + h * 16) ^ xb));
        acc = __builtin_amdgcn_mfma_f32_16x16x32_f16(af, bf, acc, 0, 0, 0);
    }

    // C/D layout (m89-verified): col = lane&15, row = (lane>>4)*4 + reg
#pragma unroll
    for (int reg = 0; reg < 4; ++reg) {
        const int rr = qi * 16 + h * 4 + reg;
        const int cc = qj * 16 + m;
        out[mat * 1024 + rr * 32 + cc] = acc[reg];
    }
}

// ---------------- Stage 2: reduce 16 chunk partials -> per-b stats (coalesced) ----
__global__ void k_reduce(const float* __restrict__ partial, float* __restrict__ red) {
    const int b = blockIdx.y;
    const int o = blockIdx.x * 128 + threadIdx.x;   // 0..2175
    float s = 0.f;
#pragma unroll
    for (int c = 0; c < 16; ++c) s += partial[(long)(c * 64 + b) * PS + o];
    red[(long)b * PS + o] = s;
}

// ---------------- Stage 3 (fused): pearson + exp + block sums + final ----------
__global__ __launch_bounds__(256)
void k_entries(const float* __restrict__ red, double* __restrict__ accs,
               unsigned* __restrict__ ctr, float* __restrict__ out) {
    const int tid = threadIdx.x;
    const int w = tid >> 6, lane = tid & 63;
    const int entry = blockIdx.x * 4 + w;
    const int mat = entry >> 10;        // 0 = pp, 1 = pn
    const int idx = entry & 1023;
    const int n = idx >> 5, m = idx & 31;

    const float* rb = red + (long)lane * PS;
    const float g    = rb[mat * 1024 + idx];
    const float sxn  = rb[2048 + n];
    const float sx2n = rb[2080 + n];
    const float sym  = rb[mat ? 2112 + m : 2048 + m];
    const float sy2m = rb[mat ? 2144 + m : 2080 + m];

    double num = (double)T_ * (double)g - (double)sxn * (double)sym;
    double vx = (double)T_ * (double)sx2n - (double)sxn * (double)sxn;
    double vy = (double)T_ * (double)sy2m - (double)sym * (double)sym;
    double contrib = 1.0 - num / sqrt(vx * vy);

#pragma unroll
    for (int off = 32; off; off >>= 1) contrib += __shfl_down(contrib, off);

    __shared__ double s_pos[4], s_neg[4];
    if (lane == 0) {
        double d = contrib * (1.0 / B_);
        double term = exp(d / 0.08);
        double p = 0.0, q = 0.0;
        if (mat == 0) { if (n < m) p = term; }   // strict upper triangle
        else q = term;
        s_pos[w] = p; s_neg[w] = q;
    }
    __syncthreads();
    if (tid == 0) {
        atomicAdd(&accs[0], s_pos[0] + s_pos[1] + s_pos[2] + s_pos[3]);
        atomicAdd(&accs[1], s_neg[0] + s_neg[1] + s_neg[2] + s_neg[3]);
        __threadfence();
        const unsigned old = atomicAdd(ctr, 1u);
        if (old == gridDim.x - 1) {              // last block finalizes
            __threadfence();
            const double p = ((volatile double*)accs)[0];
            const double q = ((volatile double*)accs)[1];
            out[0] = (float)log10(p / q + 1.0);
        }
    }
}

extern "C" void kernel_launch(void* const* d_in, const int* in_sizes, int n_in,
                              void* d_out, int out_size, void* d_ws, size_t ws_size,
                              hipStream_t stream) {
    (void)in_sizes; (void)n_in; (void)out_size; (void)ws_size;
    const float* pos = (const float*)d_in[0];
    const float* neg = (const float*)d_in[1];
    float* out = (float*)d_out;

    char* ws = (char*)d_ws;
    float* partial = (float*)ws;                               // 1024*2176*4 = 8,912,896 B
    float* red = (float*)(ws + (size_t)NBLK1 * PS * 4);        //   64*2176*4 =   557,056 B
    double* accs = (double*)(ws + (size_t)NBLK1 * PS * 4 + (size_t)64 * PS * 4);
    unsigned* ctr = (unsigned*)((char*)accs + 16);

    k_stage1<<<NBLK1, 512, 0, stream>>>(pos, neg, partial, accs, ctr);
    k_reduce<<<dim3(17, 64), 128, 0, stream>>>(partial, red);
    k_entries<<<512, 256, 0, stream>>>(red, accs, ctr, out);
}